// Round 14
// baseline (36.849 us; speedup 1.0000x reference)
//
#include <hip/hip_runtime.h>

#define B_   16
#define C_   128
#define N_   2304      // 48*48
#define ZR   256       // 2*C
#define KS   9         // k-splits: KPB=256
#define KPB  (N_/KS)   // 256
#define KC   64        // k per staged chunk
#define NCH  (KPB/KC)  // 4
#define NRB  128       // redfin grid

typedef __bf16 bf16x8 __attribute__((ext_vector_type(8)));
typedef float  f32x4  __attribute__((ext_vector_type(4)));

#define AS1(p) (const __attribute__((address_space(1))) void*)(p)
#define AS3(p) (__attribute__((address_space(3))) void*)(p)

struct Ctrl { double sum; unsigned done2; unsigned pad; };

__device__ __forceinline__ ushort rne16(float f) {
    unsigned u = __float_as_uint(f);
    return (ushort)((u + 0x7FFFu + ((u >> 16) & 1u)) >> 16);   // RNE bf16
}

// ---------------- kernel 1: norms + normalize + bf16 convert (float4) ----
// (verbatim best-known; block 0 re-zeroes ctrl)
__global__ __launch_bounds__(256) void nc_k(const float* __restrict__ pred,
                                            const float* __restrict__ targ,
                                            ushort* __restrict__ Z,
                                            Ctrl* __restrict__ ctrl) {
    int blk  = blockIdx.x;
    int t    = threadIdx.x;
    if (blk == 0 && t == 0) {
        ctrl->sum   = 0.0;
        ctrl->done2 = 0u;
    }
    int b    = blk / 72;
    int rem  = blk % 72;
    int side = rem / 36;
    int n0   = (rem % 36) * 64;
    int g  = t & 15;
    int rc = t >> 4;

    __shared__ float4 rp[16][16];
    __shared__ float4 rq[4][16];
    __shared__ float4 rn4[16];

    const float* src = (side ? targ : pred) + (size_t)b * C_ * N_ + n0 + 4 * g;
    float4 raw[8];
    float4 sq = make_float4(0.f, 0.f, 0.f, 0.f);
#pragma unroll
    for (int i = 0; i < 8; ++i) {
        raw[i] = *(const float4*)(src + (size_t)(rc * 8 + i) * N_);
        sq.x = fmaf(raw[i].x, raw[i].x, sq.x);
        sq.y = fmaf(raw[i].y, raw[i].y, sq.y);
        sq.z = fmaf(raw[i].z, raw[i].z, sq.z);
        sq.w = fmaf(raw[i].w, raw[i].w, sq.w);
    }
    rp[rc][g] = sq;
    __syncthreads();
    if (t < 64) {
        int gg = t & 15, h = t >> 4;
        float4 a0 = rp[h * 4 + 0][gg], a1 = rp[h * 4 + 1][gg];
        float4 a2 = rp[h * 4 + 2][gg], a3 = rp[h * 4 + 3][gg];
        rq[h][gg] = make_float4(a0.x + a1.x + a2.x + a3.x,
                                a0.y + a1.y + a2.y + a3.y,
                                a0.z + a1.z + a2.z + a3.z,
                                a0.w + a1.w + a2.w + a3.w);
    }
    __syncthreads();
    if (t < 16) {
        float4 a0 = rq[0][t], a1 = rq[1][t], a2 = rq[2][t], a3 = rq[3][t];
        float4 s = make_float4(a0.x + a1.x + a2.x + a3.x,
                               a0.y + a1.y + a2.y + a3.y,
                               a0.z + a1.z + a2.z + a3.z,
                               a0.w + a1.w + a2.w + a3.w);
        rn4[t] = make_float4(rsqrtf(fmaxf(s.x, 1e-20f)),
                             rsqrtf(fmaxf(s.y, 1e-20f)),
                             rsqrtf(fmaxf(s.z, 1e-20f)),
                             rsqrtf(fmaxf(s.w, 1e-20f)));
    }
    __syncthreads();
    float4 rr = rn4[g];
    ushort* dst = Z + (size_t)(b * ZR + side * C_) * N_ + n0 + 4 * g;
#pragma unroll
    for (int i = 0; i < 8; ++i) {
        ushort4 pk;
        pk.x = rne16(raw[i].x * rr.x);
        pk.y = rne16(raw[i].y * rr.y);
        pk.z = rne16(raw[i].z * rr.z);
        pk.w = rne16(raw[i].w * rr.w);
        *(ushort4*)(dst + (size_t)(rc * 8 + i) * N_) = pk;   // 8B store
    }
}

// ------------- kernel 2: full W = Z Z^T per (b, ksplit), 1x staging -------
// grid: B_*KS = 144 blocks, 512 threads (8 waves). Each block stages the
// FULL 256-row Z slice for its k-range exactly ONCE (R12/R13 lesson: gram
// was bound by 3x-redundant staged bytes, 56.6MB; now 18.9MB total) and
// computes all 16 64x64 tiles of W. Wave w: row-band ti=w>>1, col tiles
// tj=(w&1)*2 + {0,1}; acc 2x4x4 f32x4 = 128 VGPR (launch_bounds(512,2)).
// Epilogue: 2-phase LDS repack -> bf16 W (coalesced uint4 stores).
__global__ __launch_bounds__(512, 2) void gram_k(const ushort* __restrict__ Z,
                                                 ushort* __restrict__ Wp) {
    int blk = blockIdx.x;
    int b = blk / KS;
    int s = blk % KS;

    int t    = threadIdx.x;
    int lane = t & 63;
    int w    = t >> 6;                  // 0..7
    int ti   = w >> 1;                  // row band 0..3
    int tj0  = (w & 1) * 2;             // col tile pair base

    __shared__ float4 lds[4096];        // 64 KB: 2 dbuf x (256 rows x 8 gran)

    const ushort* Zb = Z + (size_t)b * ZR * N_;

    f32x4 acc[2][4][4];
#pragma unroll
    for (int tt = 0; tt < 2; ++tt)
#pragma unroll
        for (int m = 0; m < 4; ++m)
#pragma unroll
            for (int n = 0; n < 4; ++n) acc[tt][m][n] = (f32x4){0.f,0.f,0.f,0.f};

    auto stage = [&](int dbuf, int ch) {
        int kc0 = s * KPB + ch * KC;
        float4* base = lds + dbuf * 2048;
#pragma unroll
        for (int it = 0; it < 4; ++it) {
            int idx = it * 512 + t;             // 0..2047
            int r   = idx >> 3;                 // row 0..255
            int gl  = (idx & 7) ^ (r & 7);      // involution swizzle
            const ushort* gp = Zb + (size_t)r * N_ + kc0 + gl * 8;
            __builtin_amdgcn_global_load_lds(AS1(gp), AS3(base + idx), 16, 0, 0);
        }
    };

    auto compute = [&](int dbuf) {
        const bf16x8* L = (const bf16x8*)(lds + dbuf * 2048);
#pragma unroll
        for (int kk = 0; kk < 2; ++kk) {
            int gl = kk * 4 + (lane >> 4);
            bf16x8 aA[4];
#pragma unroll
            for (int m = 0; m < 4; ++m) {
                int r = ti * 64 + m * 16 + (lane & 15);
                aA[m] = L[r * 8 + (gl ^ (r & 7))];
            }
#pragma unroll
            for (int tt = 0; tt < 2; ++tt) {
                int tj = tj0 + tt;
                bf16x8 aB[4];
#pragma unroll
                for (int n = 0; n < 4; ++n) {
                    int r = tj * 64 + n * 16 + (lane & 15);
                    aB[n] = L[r * 8 + (gl ^ (r & 7))];
                }
#pragma unroll
                for (int m = 0; m < 4; ++m)
#pragma unroll
                    for (int n = 0; n < 4; ++n)
                        acc[tt][m][n] = __builtin_amdgcn_mfma_f32_16x16x32_bf16(
                            aA[m], aB[n], acc[tt][m][n], 0, 0, 0);
            }
        }
    };

    stage(0, 0);
    int buf = 0;
    for (int ch = 0; ch < NCH; ++ch) {
        __syncthreads();                    // chunk ch landed
        if (ch + 1 < NCH) stage(buf ^ 1, ch + 1);
        compute(buf);
        buf ^= 1;
    }

    // ---- epilogue: 2 phases by col-half; LDS = ushort[256][128] = 64KB ----
    ushort* Ls  = (ushort*)lds;
    ushort* Wsb = Wp + (size_t)(s * B_ + b) * ZR * ZR;
#pragma unroll
    for (int ph = 0; ph < 2; ++ph) {
        __syncthreads();                    // lds free / previous phase done
        if ((w & 1) == ph) {                // my tiles are in col-half ph
#pragma unroll
            for (int tt = 0; tt < 2; ++tt)
#pragma unroll
                for (int m = 0; m < 4; ++m)
#pragma unroll
                    for (int n = 0; n < 4; ++n)
#pragma unroll
                        for (int v = 0; v < 4; ++v) {
                            int row = ti * 64 + m * 16 + (lane >> 4) * 4 + v;
                            int col = tt * 64 + n * 16 + (lane & 15);
                            Ls[row * 128 + col] = rne16(acc[tt][m][n][v]);
                        }
        }
        __syncthreads();
        const uint4* L4 = (const uint4*)lds;
#pragma unroll
        for (int i = 0; i < 8; ++i) {       // 4096 uint4 = 64KB
            int u   = i * 512 + t;
            int row = u >> 4;
            int cg  = u & 15;
            *(uint4*)(Wsb + (size_t)row * ZR + ph * 128 + cg * 8) = L4[u];
        }
    }
}

// ------------- kernel 3: reduce + finalize (tail atomics, no spin) -------
// grid: NRB=128 (16 b x 8 seg), 256 threads. W is full 256x256 bf16 per
// (s,b): GA=W[i,j], GB=W[128+i,128+j], P=W[128+i,j], PT=W[i,128+j] -- all
// four streams read coalesced (uint4 = 8 bf16). f32 split-sum over s=0..8,
// double contraction, RELAXED sum-add + RELEASE counter, winner writes out.
__global__ __launch_bounds__(256) void redfin_k(const ushort* __restrict__ Wp,
                                                Ctrl* __restrict__ ctrl,
                                                float* __restrict__ out) {
    int blk = blockIdx.x;
    int b   = blk >> 3;
    int seg = blk & 7;
    int t   = threadIdx.x;
    int idx8 = seg * 256 + t;               // 0..2047 (8-elem groups of 128x128)
    int i    = idx8 >> 4;                   // row 0..127
    int jg   = idx8 & 15;                   // col group (8 cols)

    const uint4* W4b = (const uint4*)Wp;
    float ga[8], gb[8], p[8], pt[8];
#pragma unroll
    for (int e = 0; e < 8; ++e) { ga[e] = gb[e] = p[e] = pt[e] = 0.f; }

#pragma unroll
    for (int s = 0; s < KS; ++s) {
        const uint4* W4 = W4b + (size_t)(s * B_ + b) * 8192;   // 128KB/(16B)
        uint4 a0 = W4[i * 32 + jg];                 // GA[i, jg]
        uint4 a1 = W4[(128 + i) * 32 + 16 + jg];    // GB
        uint4 a2 = W4[(128 + i) * 32 + jg];         // P
        uint4 a3 = W4[i * 32 + 16 + jg];            // PT
        const unsigned* u0 = (const unsigned*)&a0;
        const unsigned* u1 = (const unsigned*)&a1;
        const unsigned* u2 = (const unsigned*)&a2;
        const unsigned* u3 = (const unsigned*)&a3;
#pragma unroll
        for (int h = 0; h < 4; ++h) {
            ga[2 * h]     += __uint_as_float(u0[h] << 16);
            ga[2 * h + 1] += __uint_as_float(u0[h] & 0xFFFF0000u);
            gb[2 * h]     += __uint_as_float(u1[h] << 16);
            gb[2 * h + 1] += __uint_as_float(u1[h] & 0xFFFF0000u);
            p[2 * h]      += __uint_as_float(u2[h] << 16);
            p[2 * h + 1]  += __uint_as_float(u2[h] & 0xFFFF0000u);
            pt[2 * h]     += __uint_as_float(u3[h] << 16);
            pt[2 * h + 1] += __uint_as_float(u3[h] & 0xFFFF0000u);
        }
    }
    double v = 0.0;
#pragma unroll
    for (int e = 0; e < 8; ++e)
        v += (double)ga[e] * (double)gb[e] - (double)p[e] * (double)pt[e];

    __shared__ double sd[4];
#pragma unroll
    for (int o = 32; o > 0; o >>= 1) v += __shfl_down(v, o, 64);
    if ((t & 63) == 0) sd[t >> 6] = v;
    __syncthreads();
    if (t == 0) {
        double bv = sd[0] + sd[1] + sd[2] + sd[3];
        __hip_atomic_fetch_add(&ctrl->sum, bv, __ATOMIC_RELAXED,
                               __HIP_MEMORY_SCOPE_AGENT);
        unsigned c = __hip_atomic_fetch_add(&ctrl->done2, 1u, __ATOMIC_RELEASE,
                                            __HIP_MEMORY_SCOPE_AGENT);
        if (c == NRB - 1) {
            double tot = __hip_atomic_fetch_add(&ctrl->sum, 0.0,
                                                __ATOMIC_ACQUIRE,
                                                __HIP_MEMORY_SCOPE_AGENT);
            out[0] = (float)(2.0 * tot
                             / ((double)B_ * (double)N_ * (double)N_));
        }
    }
}

extern "C" void kernel_launch(void* const* d_in, const int* in_sizes, int n_in,
                              void* d_out, int out_size, void* d_ws, size_t ws_size,
                              hipStream_t stream) {
    const float* pred = (const float*)d_in[0];
    const float* targ = (const float*)d_in[1];
    float* out = (float*)d_out;

    // workspace layout (bytes):
    //   Z   : B_*ZR*N_*2        = 18,874,368  (bf16, normalized)
    //   Wp  : KS*B_*ZR*ZR*2     = 18,874,368  (bf16 full-W partials)
    //   ctrl: 16 bytes -- re-zeroed by nc_k each launch
    char*   ws = (char*)d_ws;
    ushort* Z  = (ushort*)ws;
    ushort* Wp = (ushort*)(ws + (size_t)B_ * ZR * N_ * 2);
    Ctrl*   ct = (Ctrl*)(ws + (size_t)B_ * ZR * N_ * 2
                            + (size_t)KS * B_ * ZR * ZR * 2);

    nc_k<<<B_ * 2 * 36, 256, 0, stream>>>(pred, targ, Z, ct);
    gram_k<<<B_ * KS, 512, 0, stream>>>(Z, Wp);
    redfin_k<<<NRB, 256, 0, stream>>>(Wp, ct, out);
}